// Round 19
// baseline (1949.297 us; speedup 1.0000x reference)
//
#include <hip/hip_runtime.h>
#include <hip/hip_bf16.h>

// Shapes: B=8, L=S=1024, D=1024, H=16, E=64, TOP_K=8.
// d_out = [ out (B*L*D f32) | A (B*H*L*S f32) ]
//
// PASSING reference model (R16, keep bit-exact):
//  - projections: ascending-k f32 FMA chain within K-panels {512,512}
//    (BLIS fixed KC=512), panels combined by single f32 adds; +bias, relu.
//  - scores: ONE ascending-e f32 FMA chain per score (K=64 single panel).
//  - top-8: thresh = 8th largest (multiplicity-counted); kept = s >= thresh.
//
// R19: (1) top-8+softmax fused into the score kernel (scores held in
// acc[8][16] registers; single masked A write - kills the 537MB round
// trip + 337us topk_pass2). (2) GEMM retiled to 128x64 (8x4/thread),
// same bit-exact chain.

#define B_ 8
#define L_ 1024
#define S_ 1024
#define D_ 1024
#define H_ 16
#define E_ 64
#define TOPK_ 8

// ---------------------------------------------------------------------------
// C = A(MxK,row) * B(NxK,row)^T + bias, optional relu. f32; ascending-k FMA
// chain within BLIS panels {512,512} (flush after k-tiles 31, 63), f32 adds
// across panels. 128x64 tile, 8x4 per thread. (Bit-exact - do not reorder.)
// ---------------------------------------------------------------------------
template <int RELU>
__global__ __launch_bounds__(256) void gemm_abt(
    const float* __restrict__ A, const float* __restrict__ Bm,
    const float* __restrict__ bias, float* __restrict__ C,
    int M, int N, int K, int lda, int ldb, int ldc) {
  __shared__ float As[16][132];
  __shared__ float Bs[16][68];

  const int t = threadIdx.x;
  const int tx = t & 15, ty = t >> 4;
  const int m0 = blockIdx.y * 128, n0 = blockIdx.x * 64;

  float acc[8][4], tot[8][4];
#pragma unroll
  for (int r = 0; r < 8; ++r)
#pragma unroll
    for (int c = 0; c < 4; ++c) {
      acc[r][c] = 0.0f;
      tot[r][c] = 0.0f;
    }

  const int ntiles = K / 16;
  for (int ti = 0; ti < ntiles; ++ti) {
    const int kt = ti * 16;
    __syncthreads();
#pragma unroll
    for (int i = 0; i < 8; ++i) {
      const int idx = i * 256 + t;
      const int r = idx >> 4, kk = idx & 15;
      As[kk][r] = A[(long long)(m0 + r) * lda + kt + kk];
    }
#pragma unroll
    for (int i = 0; i < 4; ++i) {
      const int idx = i * 256 + t;
      const int r = idx >> 4, kk = idx & 15;
      Bs[kk][r] = Bm[(long long)(n0 + r) * ldb + kt + kk];
    }
    __syncthreads();
#pragma unroll
    for (int kk = 0; kk < 16; ++kk) {
      const float4 a0 = *reinterpret_cast<const float4*>(&As[kk][ty * 8]);
      const float4 a1 = *reinterpret_cast<const float4*>(&As[kk][ty * 8 + 4]);
      const float4 b4 = *reinterpret_cast<const float4*>(&Bs[kk][tx * 4]);
      const float av[8] = {a0.x, a0.y, a0.z, a0.w, a1.x, a1.y, a1.z, a1.w};
      const float bv[4] = {b4.x, b4.y, b4.z, b4.w};
#pragma unroll
      for (int r = 0; r < 8; ++r)
#pragma unroll
        for (int c = 0; c < 4; ++c) acc[r][c] = fmaf(av[r], bv[c], acc[r][c]);
    }
    const bool flush =
        (K == 1024) ? (ti == 31 || ti == 63) : (ti == ntiles - 1);
    if (flush) {
#pragma unroll
      for (int r = 0; r < 8; ++r)
#pragma unroll
        for (int c = 0; c < 4; ++c) {
          tot[r][c] = __fadd_rn(tot[r][c], acc[r][c]);
          acc[r][c] = 0.0f;
        }
    }
  }

#pragma unroll
  for (int r = 0; r < 8; ++r) {
    const int m = m0 + ty * 8 + r;
#pragma unroll
    for (int c = 0; c < 4; ++c) {
      const int n = n0 + tx * 4 + c;
      float v = tot[r][c];
      if (bias) v = __fadd_rn(v, bias[n]);
      if (RELU) v = fmaxf(v, 0.0f);
      C[(long long)m * ldc + n] = v;
    }
  }
}

// ---------------------------------------------------------------------------
// Transpose K head-slices: Kt[(b*16+h)*64 + e][s] = Kf[(b*1024+s)][h*64+e].
// ---------------------------------------------------------------------------
__global__ __launch_bounds__(256) void transpose_k(const float* __restrict__ Kf,
                                                   float* __restrict__ Kt) {
  __shared__ float tl[64][65];
  const int bh = blockIdx.y;
  const int b = bh >> 4, h = bh & 15;
  const int s0 = blockIdx.x * 64;
  const int t = threadIdx.x;
#pragma unroll
  for (int i = 0; i < 16; ++i) {
    const int idx = i * 256 + t;
    const int sr = idx >> 6, e = idx & 63;
    tl[sr][e] = Kf[(((long long)(b << 10) + s0 + sr) << 10) + (h << 6) + e];
  }
  __syncthreads();
#pragma unroll
  for (int i = 0; i < 16; ++i) {
    const int idx = i * 256 + t;
    const int er = idx >> 6, s = idx & 63;
    Kt[(((long long)(bh << 6) + er) << 10) + s0 + s] = tl[s][er];
  }
}

// ---------------------------------------------------------------------------
// Fused scores + top-8 + softmax. Block = 256 threads = 4 waves = 32 rows
// (same b,h). Wave holds 8 q-vectors in regs (lane e holds q[e], readlane
// broadcast); K tiles [64][256] staged conflict-free from Kt. Full row kept
// in acc[8][16] registers; per-row top-8 (multiplicity-correct) + softmax
// in-wave; single masked coalesced A write + compact (idx,w) lists.
// Score chain: ascending e, fmaf - bit-exact vs reference.
// ---------------------------------------------------------------------------
__global__ __launch_bounds__(256, 2) void score_topk_fused(
    const float* __restrict__ Qf, const float* __restrict__ Kt,
    float* __restrict__ A, int* __restrict__ outIdx,
    float* __restrict__ outW, int* __restrict__ outCnt) {
#pragma clang fp contract(off)
  __shared__ float Ks[64][256];

  const int t = threadIdx.x;
  const int wv = t >> 6, u = t & 63;
  const int row0 = blockIdx.x * 32;
  const int b = row0 >> 14, h = (row0 >> 10) & 15;
  const int l0 = row0 & 1023;
  const int bh = (b << 4) + h;

  float qreg[8];
  const int rbase = l0 + wv * 8;
#pragma unroll
  for (int r = 0; r < 8; ++r)
    qreg[r] = Qf[(((long long)(b << 10) + rbase + r) << 10) + (h << 6) + u];

  const float* KtBase = Kt + ((long long)(bh << 6) << 10);  // [64][1024]

  float acc[8][16];
#pragma unroll
  for (int r = 0; r < 8; ++r)
#pragma unroll
    for (int j = 0; j < 16; ++j) acc[r][j] = 0.0f;

#pragma unroll
  for (int wt = 0; wt < 4; ++wt) {
    __syncthreads();
#pragma unroll
    for (int i = 0; i < 16; ++i) {
      const int idx = i * 256 + t;
      const int e = idx >> 6, uu = idx & 63;
      *reinterpret_cast<float4*>(&Ks[e][4 * uu]) =
          *reinterpret_cast<const float4*>(
              &KtBase[((long long)e << 10) + wt * 256 + 4 * uu]);
    }
    __syncthreads();

#pragma unroll 8
    for (int e = 0; e < 64; ++e) {
      const float4 k4 = *reinterpret_cast<const float4*>(&Ks[e][4 * u]);
#pragma unroll
      for (int r = 0; r < 8; ++r) {
        const float qv = __uint_as_float(
            __builtin_amdgcn_readlane(__float_as_uint(qreg[r]), e));
        acc[r][wt * 4 + 0] = fmaf(qv, k4.x, acc[r][wt * 4 + 0]);
        acc[r][wt * 4 + 1] = fmaf(qv, k4.y, acc[r][wt * 4 + 1]);
        acc[r][wt * 4 + 2] = fmaf(qv, k4.z, acc[r][wt * 4 + 2]);
        acc[r][wt * 4 + 3] = fmaf(qv, k4.w, acc[r][wt * 4 + 3]);
      }
    }
  }

  // ---- per-row top-8 + softmax + write (r unrolled: static acc indexing) ----
#pragma unroll
  for (int r = 0; r < 8; ++r) {
    float s[16];
#pragma unroll
    for (int j = 0; j < 16; ++j) s[j] = acc[r][j];

    unsigned act = 0xFFFFu;
    float rowmax = 0.f, thresh = 0.f;
    for (int it = 0; it < TOPK_; ++it) {
      float lm = -INFINITY;
#pragma unroll
      for (int j = 0; j < 16; ++j)
        if (act & (1u << j)) lm = fmaxf(lm, s[j]);
      float m = lm;
#pragma unroll
      for (int d = 1; d < 64; d <<= 1) m = fmaxf(m, __shfl_xor(m, d));
      if (it == 0) rowmax = m;
      thresh = m;
      const bool has = (lm == m);
      const unsigned long long msk = __ballot(has);
      const int owner = __ffsll((long long)msk) - 1;
      if (u == owner) {
        bool done = false;
#pragma unroll
        for (int j = 0; j < 16; ++j) {
          if (!done && (act & (1u << j)) && s[j] == m) {
            act &= ~(1u << j);
            done = true;
          }
        }
      }
    }

    float zsum = 0.f;
#pragma unroll
    for (int j = 0; j < 16; ++j) {
      const bool kept = (s[j] >= thresh);
      const float e = kept ? expf((s[j] - rowmax) * 0.125f) : 0.0f;
      acc[r][j] = e;  // reuse as e16
      zsum += e;
    }
#pragma unroll
    for (int d = 1; d < 64; d <<= 1) zsum += __shfl_xor(zsum, d);
    const float inv = 1.0f / zsum;

    const long long row = row0 + wv * 8 + r;
    float* a = A + (row << 10);
    int cnt = 0;
#pragma unroll
    for (int j = 0; j < 16; ++j) {
      const bool kept = (s[j] >= thresh);
      const float w = acc[r][j] * inv;
      acc[r][j] = kept ? w : 0.0f;
      const unsigned long long mk = __ballot(kept);
      if (kept) {
        const int pos = cnt + __popcll(mk & ((1ull << u) - 1ull));
        if (pos < 16) {
          const int col = (j >> 2) * 256 + 4 * u + (j & 3);
          outIdx[row * 16 + pos] = col;
          outW[row * 16 + pos] = w;
        }
      }
      cnt += __popcll(mk);
    }
    if (u == 0) outCnt[row] = cnt < 16 ? cnt : 16;

#pragma unroll
    for (int wt = 0; wt < 4; ++wt) {
      float4 o;
      o.x = acc[r][wt * 4 + 0];
      o.y = acc[r][wt * 4 + 1];
      o.z = acc[r][wt * 4 + 2];
      o.w = acc[r][wt * 4 + 3];
      *reinterpret_cast<float4*>(&a[wt * 256 + 4 * u]) = o;
    }
  }
}

// ---------------------------------------------------------------------------
// Sparse A*v from compact lists. One wave per row (lane = e).
// ---------------------------------------------------------------------------
__global__ __launch_bounds__(256) void vagg_kernel(
    const int* __restrict__ idx, const float* __restrict__ w,
    const int* __restrict__ cnt, const float* __restrict__ Vp,
    float* __restrict__ Vagg) {
  const int wave = threadIdx.x >> 6;
  const int lane = threadIdx.x & 63;
  const long long row = (long long)blockIdx.x * 4 + wave;
  const int b = (int)(row >> 14);
  const int h = (int)((row >> 10) & 15);
  const int l = (int)(row & 1023);
  const int n = cnt[row];
  float acc = 0.0f;
  for (int i = 0; i < n; ++i) {
    const int sI = idx[row * 16 + i];
    const float ww = w[row * 16 + i];
    acc += ww * Vp[((long long)((b << 10) + sI) << 10) + (h << 6) + lane];
  }
  Vagg[((long long)((b << 10) + l) << 10) + (h << 6) + lane] = acc;
}

extern "C" void kernel_launch(void* const* d_in, const int* in_sizes, int n_in,
                              void* d_out, int out_size, void* d_ws,
                              size_t ws_size, hipStream_t stream) {
  const float* queries = (const float*)d_in[0];
  const float* keys = (const float*)d_in[1];
  const float* values = (const float*)d_in[2];
  const float* Wq = (const float*)d_in[3];
  const float* bq = (const float*)d_in[4];
  const float* Wk = (const float*)d_in[5];
  const float* bk = (const float*)d_in[6];
  const float* Wv = (const float*)d_in[7];
  const float* bv = (const float*)d_in[8];
  const float* Wo = (const float*)d_in[9];
  const float* bo = (const float*)d_in[10];

  float* out = (float*)d_out;                   // [B,L,D]
  float* Aout = out + (long long)B_ * L_ * D_;  // [B,H,L,S]

  char* ws = (char*)d_ws;
  const size_t MD = (size_t)B_ * L_ * D_ * sizeof(float);  // 33.55 MB
  const size_t NL = (size_t)B_ * H_ * L_;                   // 131072 rows
  float* Qf = (float*)ws;
  float* Kf = (float*)(ws + MD);
  float* Kt = (float*)(ws + 2 * MD);
  int* tIdx = (int*)(ws + 3 * MD);
  float* tW = (float*)(ws + 3 * MD + NL * 16 * 4);
  int* tCnt = (int*)(ws + 3 * MD + NL * 16 * 8);
  float* Vb = (float*)(ws + 3 * MD + NL * 16 * 8 + NL * 4);
  float* Vagg = Kt;  // Kt dead after score_topk_fused

  const dim3 blk(256);
  const int M = B_ * L_;  // 8192

  // Q = relu(queries @ Wq^T + bq)   [bit-exact chain]
  gemm_abt<1><<<dim3(16, M / 128), blk, 0, stream>>>(queries, Wq, bq, Qf, M,
                                                     D_, D_, D_, D_, D_);
  // K = keys @ Wk^T + bk            [bit-exact chain]
  gemm_abt<0><<<dim3(16, M / 128), blk, 0, stream>>>(keys, Wk, bk, Kf, M, D_,
                                                     D_, D_, D_, D_);
  // Kt[b,h,e,s] = Kf[b,s,h,e]
  transpose_k<<<dim3(16, B_ * H_), blk, 0, stream>>>(Kf, Kt);

  // fused scores + top-8 + softmax -> A + compact lists
  score_topk_fused<<<(int)(NL / 32), blk, 0, stream>>>(Qf, Kt, Aout, tIdx, tW,
                                                       tCnt);

  // V = relu(values @ Wv^T + bv)
  gemm_abt<1><<<dim3(16, M / 128), blk, 0, stream>>>(values, Wv, bv, Vb, M, D_,
                                                     D_, D_, D_, D_);

  // Vagg[b,l,h,:] = sum_s A * v   (writes into Kt slot)
  vagg_kernel<<<(int)(NL / 4), blk, 0, stream>>>(tIdx, tW, tCnt, Vb, Vagg);

  // out = Vagg @ Wo^T + bo
  gemm_abt<0><<<dim3(16, M / 128), blk, 0, stream>>>(Vagg, Wo, bo, out, M, D_,
                                                     D_, D_, D_, D_);
}

// Round 20
// 1661.643 us; speedup vs baseline: 1.1731x; 1.1731x over previous
//
#include <hip/hip_runtime.h>
#include <hip/hip_bf16.h>

// Shapes: B=8, L=S=1024, D=1024, H=16, E=64, TOP_K=8.
// d_out = [ out (B*L*D f32) | A (B*H*L*S f32) ]
//
// PASSING reference model (R16, keep bit-exact):
//  - projections: ascending-k f32 FMA chain within K-panels {512,512}
//    (BLIS fixed KC=512), panels combined by single f32 adds; +bias, relu.
//  - scores: ONE ascending-e f32 FMA chain per score (K=64 single panel).
//  - top-8: thresh = 8th largest (multiplicity-counted); kept = s >= thresh.
//
// R20: fused score+top8+softmax with fixed resources: 4 rows/wave
// (acc[4][16]=64 VGPR, no spill - R19 spilled at 8 rows), 32KB LDS via
// e-split staging (Ks[32][256], 2 e-halves x 4 col-tiles; per-col e still
// ascends 0..63 -> bit-exact chain). GEMM reverted to 64x64 tile.

#define B_ 8
#define L_ 1024
#define S_ 1024
#define D_ 1024
#define H_ 16
#define E_ 64
#define TOPK_ 8

// ---------------------------------------------------------------------------
// C = A(MxK,row) * B(NxK,row)^T + bias, optional relu. f32; ascending-k FMA
// chain within BLIS panels {512,512} (flush after k-tiles 31, 63), f32 adds
// across panels. (Bit-exact - do not reorder.)
// ---------------------------------------------------------------------------
template <int RELU>
__global__ __launch_bounds__(256) void gemm_abt(
    const float* __restrict__ A, const float* __restrict__ Bm,
    const float* __restrict__ bias, float* __restrict__ C,
    int M, int N, int K, int lda, int ldb, int ldc) {
  __shared__ float As[16][68];
  __shared__ float Bs[16][68];

  const int t = threadIdx.x;
  const int tx = t & 15, ty = t >> 4;
  const int m0 = blockIdx.y * 64, n0 = blockIdx.x * 64;

  float acc[4][4], tot[4][4];
#pragma unroll
  for (int r = 0; r < 4; ++r)
#pragma unroll
    for (int c = 0; c < 4; ++c) {
      acc[r][c] = 0.0f;
      tot[r][c] = 0.0f;
    }

  const int ntiles = K / 16;
  for (int ti = 0; ti < ntiles; ++ti) {
    const int kt = ti * 16;
    __syncthreads();
#pragma unroll
    for (int i = 0; i < 4; ++i) {
      const int idx = t + 256 * i;
      const int r = idx >> 4, kk = idx & 15;
      As[kk][r] = A[(long long)(m0 + r) * lda + kt + kk];
      Bs[kk][r] = Bm[(long long)(n0 + r) * ldb + kt + kk];
    }
    __syncthreads();
#pragma unroll
    for (int kk = 0; kk < 16; ++kk) {
      const float4 a4 = *reinterpret_cast<const float4*>(&As[kk][ty * 4]);
      const float4 b4 = *reinterpret_cast<const float4*>(&Bs[kk][tx * 4]);
      const float av[4] = {a4.x, a4.y, a4.z, a4.w};
      const float bv[4] = {b4.x, b4.y, b4.z, b4.w};
#pragma unroll
      for (int r = 0; r < 4; ++r)
#pragma unroll
        for (int c = 0; c < 4; ++c) acc[r][c] = fmaf(av[r], bv[c], acc[r][c]);
    }
    const bool flush =
        (K == 1024) ? (ti == 31 || ti == 63) : (ti == ntiles - 1);
    if (flush) {
#pragma unroll
      for (int r = 0; r < 4; ++r)
#pragma unroll
        for (int c = 0; c < 4; ++c) {
          tot[r][c] = __fadd_rn(tot[r][c], acc[r][c]);
          acc[r][c] = 0.0f;
        }
    }
  }

#pragma unroll
  for (int r = 0; r < 4; ++r) {
    const int m = m0 + ty * 4 + r;
#pragma unroll
    for (int c = 0; c < 4; ++c) {
      const int n = n0 + tx * 4 + c;
      float v = tot[r][c];
      if (bias) v = __fadd_rn(v, bias[n]);
      if (RELU) v = fmaxf(v, 0.0f);
      C[(long long)m * ldc + n] = v;
    }
  }
}

// ---------------------------------------------------------------------------
// Transpose K head-slices: Kt[(b*16+h)*64 + e][s] = Kf[(b*1024+s)][h*64+e].
// ---------------------------------------------------------------------------
__global__ __launch_bounds__(256) void transpose_k(const float* __restrict__ Kf,
                                                   float* __restrict__ Kt) {
  __shared__ float tl[64][65];
  const int bh = blockIdx.y;
  const int b = bh >> 4, h = bh & 15;
  const int s0 = blockIdx.x * 64;
  const int t = threadIdx.x;
#pragma unroll
  for (int i = 0; i < 16; ++i) {
    const int idx = i * 256 + t;
    const int sr = idx >> 6, e = idx & 63;
    tl[sr][e] = Kf[(((long long)(b << 10) + s0 + sr) << 10) + (h << 6) + e];
  }
  __syncthreads();
#pragma unroll
  for (int i = 0; i < 16; ++i) {
    const int idx = i * 256 + t;
    const int er = idx >> 6, s = idx & 63;
    Kt[(((long long)(bh << 6) + er) << 10) + s0 + s] = tl[s][er];
  }
}

// ---------------------------------------------------------------------------
// Fused scores + top-8 + softmax. Block = 256 threads = 4 waves; each wave
// owns 4 rows (16 rows/block, same b,h). Lane e holds q[e] (readlane
// broadcast). K staged as Ks[32][256]: 2 e-halves x 4 col-tiles of 256;
// per column, e ascends 0..63 across the two halves -> bit-exact fmaf
// chain. acc[4][16] stays in registers (64 VGPR). Per-row top-8
// (multiplicity-correct) + softmax in-wave; masked A write + compact lists.
// ---------------------------------------------------------------------------
__global__ __launch_bounds__(256, 4) void score_topk_fused(
    const float* __restrict__ Qf, const float* __restrict__ Kt,
    float* __restrict__ A, int* __restrict__ outIdx,
    float* __restrict__ outW, int* __restrict__ outCnt) {
#pragma clang fp contract(off)
  __shared__ float Ks[32][256];

  const int t = threadIdx.x;
  const int wv = t >> 6, u = t & 63;
  const int row0 = blockIdx.x * 16;  // 16 consecutive rows, same (b,h)
  const int b = row0 >> 14, h = (row0 >> 10) & 15;
  const int bh = (b << 4) + h;
  const int rbase = (row0 & 1023) + wv * 4;

  float qreg[4];
#pragma unroll
  for (int r = 0; r < 4; ++r)
    qreg[r] = Qf[(((long long)(b << 10) + rbase + r) << 10) + (h << 6) + u];

  const float* KtBase = Kt + ((long long)(bh << 6) << 10);  // [64][1024]

  float acc[4][16];
#pragma unroll
  for (int r = 0; r < 4; ++r)
#pragma unroll
    for (int j = 0; j < 16; ++j) acc[r][j] = 0.0f;

#pragma unroll
  for (int et = 0; et < 2; ++et) {
#pragma unroll
    for (int wt = 0; wt < 4; ++wt) {
      __syncthreads();
#pragma unroll
      for (int i = 0; i < 8; ++i) {
        const int idx = i * 256 + t;
        const int el = idx >> 6, uu = idx & 63;
        *reinterpret_cast<float4*>(&Ks[el][4 * uu]) =
            *reinterpret_cast<const float4*>(
                &KtBase[((long long)(et * 32 + el) << 10) + wt * 256 +
                        4 * uu]);
      }
      __syncthreads();

#pragma unroll 8
      for (int el = 0; el < 32; ++el) {
        const float4 k4 = *reinterpret_cast<const float4*>(&Ks[el][4 * u]);
#pragma unroll
        for (int r = 0; r < 4; ++r) {
          const float qv = __uint_as_float(__builtin_amdgcn_readlane(
              __float_as_uint(qreg[r]), et * 32 + el));
          acc[r][wt * 4 + 0] = fmaf(qv, k4.x, acc[r][wt * 4 + 0]);
          acc[r][wt * 4 + 1] = fmaf(qv, k4.y, acc[r][wt * 4 + 1]);
          acc[r][wt * 4 + 2] = fmaf(qv, k4.z, acc[r][wt * 4 + 2]);
          acc[r][wt * 4 + 3] = fmaf(qv, k4.w, acc[r][wt * 4 + 3]);
        }
      }
    }
  }

  // ---- per-row top-8 + softmax + write (r unrolled: static indexing) ----
#pragma unroll
  for (int r = 0; r < 4; ++r) {
    float s[16];
#pragma unroll
    for (int j = 0; j < 16; ++j) s[j] = acc[r][j];

    unsigned act = 0xFFFFu;
    float rowmax = 0.f, thresh = 0.f;
    for (int it = 0; it < TOPK_; ++it) {
      float lm = -INFINITY;
#pragma unroll
      for (int j = 0; j < 16; ++j)
        if (act & (1u << j)) lm = fmaxf(lm, s[j]);
      float m = lm;
#pragma unroll
      for (int d = 1; d < 64; d <<= 1) m = fmaxf(m, __shfl_xor(m, d));
      if (it == 0) rowmax = m;
      thresh = m;
      const bool has = (lm == m);
      const unsigned long long msk = __ballot(has);
      const int owner = __ffsll((long long)msk) - 1;
      if (u == owner) {
        bool done = false;
#pragma unroll
        for (int j = 0; j < 16; ++j) {
          if (!done && (act & (1u << j)) && s[j] == m) {
            act &= ~(1u << j);
            done = true;
          }
        }
      }
    }

    float zsum = 0.f;
#pragma unroll
    for (int j = 0; j < 16; ++j) {
      const bool kept = (s[j] >= thresh);
      const float e = kept ? expf((s[j] - rowmax) * 0.125f) : 0.0f;
      acc[r][j] = e;
      zsum += e;
    }
#pragma unroll
    for (int d = 1; d < 64; d <<= 1) zsum += __shfl_xor(zsum, d);
    const float inv = 1.0f / zsum;

    const long long row = row0 + wv * 4 + r;
    float* a = A + (row << 10);
    int cnt = 0;
#pragma unroll
    for (int j = 0; j < 16; ++j) {
      const bool kept = (s[j] >= thresh);
      const float w = acc[r][j] * inv;
      acc[r][j] = kept ? w : 0.0f;
      const unsigned long long mk = __ballot(kept);
      if (kept) {
        const int pos = cnt + __popcll(mk & ((1ull << u) - 1ull));
        if (pos < 16) {
          const int col = (j >> 2) * 256 + 4 * u + (j & 3);
          outIdx[row * 16 + pos] = col;
          outW[row * 16 + pos] = w;
        }
      }
      cnt += __popcll(mk);
    }
    if (u == 0) outCnt[row] = cnt < 16 ? cnt : 16;

#pragma unroll
    for (int wt = 0; wt < 4; ++wt) {
      float4 o;
      o.x = acc[r][wt * 4 + 0];
      o.y = acc[r][wt * 4 + 1];
      o.z = acc[r][wt * 4 + 2];
      o.w = acc[r][wt * 4 + 3];
      *reinterpret_cast<float4*>(&a[wt * 256 + 4 * u]) = o;
    }
  }
}

// ---------------------------------------------------------------------------
// Sparse A*v from compact lists. One wave per row (lane = e).
// ---------------------------------------------------------------------------
__global__ __launch_bounds__(256) void vagg_kernel(
    const int* __restrict__ idx, const float* __restrict__ w,
    const int* __restrict__ cnt, const float* __restrict__ Vp,
    float* __restrict__ Vagg) {
  const int wave = threadIdx.x >> 6;
  const int lane = threadIdx.x & 63;
  const long long row = (long long)blockIdx.x * 4 + wave;
  const int b = (int)(row >> 14);
  const int h = (int)((row >> 10) & 15);
  const int l = (int)(row & 1023);
  const int n = cnt[row];
  float acc = 0.0f;
  for (int i = 0; i < n; ++i) {
    const int sI = idx[row * 16 + i];
    const float ww = w[row * 16 + i];
    acc += ww * Vp[((long long)((b << 10) + sI) << 10) + (h << 6) + lane];
  }
  Vagg[((long long)((b << 10) + l) << 10) + (h << 6) + lane] = acc;
}

extern "C" void kernel_launch(void* const* d_in, const int* in_sizes, int n_in,
                              void* d_out, int out_size, void* d_ws,
                              size_t ws_size, hipStream_t stream) {
  const float* queries = (const float*)d_in[0];
  const float* keys = (const float*)d_in[1];
  const float* values = (const float*)d_in[2];
  const float* Wq = (const float*)d_in[3];
  const float* bq = (const float*)d_in[4];
  const float* Wk = (const float*)d_in[5];
  const float* bk = (const float*)d_in[6];
  const float* Wv = (const float*)d_in[7];
  const float* bv = (const float*)d_in[8];
  const float* Wo = (const float*)d_in[9];
  const float* bo = (const float*)d_in[10];

  float* out = (float*)d_out;                   // [B,L,D]
  float* Aout = out + (long long)B_ * L_ * D_;  // [B,H,L,S]

  char* ws = (char*)d_ws;
  const size_t MD = (size_t)B_ * L_ * D_ * sizeof(float);  // 33.55 MB
  const size_t NL = (size_t)B_ * H_ * L_;                   // 131072 rows
  float* Qf = (float*)ws;
  float* Kf = (float*)(ws + MD);
  float* Kt = (float*)(ws + 2 * MD);
  int* tIdx = (int*)(ws + 3 * MD);
  float* tW = (float*)(ws + 3 * MD + NL * 16 * 4);
  int* tCnt = (int*)(ws + 3 * MD + NL * 16 * 8);
  float* Vb = (float*)(ws + 3 * MD + NL * 16 * 8 + NL * 4);
  float* Vagg = Kt;  // Kt dead after score_topk_fused

  const dim3 blk(256);
  const int M = B_ * L_;  // 8192

  // Q = relu(queries @ Wq^T + bq)   [bit-exact chain]
  gemm_abt<1><<<dim3(16, M / 64), blk, 0, stream>>>(queries, Wq, bq, Qf, M, D_,
                                                    D_, D_, D_, D_);
  // K = keys @ Wk^T + bk            [bit-exact chain]
  gemm_abt<0><<<dim3(16, M / 64), blk, 0, stream>>>(keys, Wk, bk, Kf, M, D_,
                                                    D_, D_, D_, D_);
  // Kt[b,h,e,s] = Kf[b,s,h,e]
  transpose_k<<<dim3(16, B_ * H_), blk, 0, stream>>>(Kf, Kt);

  // fused scores + top-8 + softmax -> A + compact lists
  score_topk_fused<<<(int)(NL / 16), blk, 0, stream>>>(Qf, Kt, Aout, tIdx, tW,
                                                       tCnt);

  // V = relu(values @ Wv^T + bv)
  gemm_abt<1><<<dim3(16, M / 64), blk, 0, stream>>>(values, Wv, bv, Vb, M, D_,
                                                    D_, D_, D_, D_);

  // Vagg[b,l,h,:] = sum_s A * v   (writes into Kt slot)
  vagg_kernel<<<(int)(NL / 4), blk, 0, stream>>>(tIdx, tW, tCnt, Vb, Vagg);

  // out = Vagg @ Wo^T + bo
  gemm_abt<0><<<dim3(16, M / 64), blk, 0, stream>>>(Vagg, Wo, bo, out, M, D_,
                                                    D_, D_, D_, D_);
}

// Round 21
// 1625.756 us; speedup vs baseline: 1.1990x; 1.0221x over previous
//
#include <hip/hip_runtime.h>
#include <hip/hip_bf16.h>

// Shapes: B=8, L=S=1024, D=1024, H=16, E=64, TOP_K=8.
// d_out = [ out (B*L*D f32) | A (B*H*L*S f32) ]
//
// PASSING reference model (R16, keep bit-exact):
//  - projections: ascending-k f32 FMA chain within K-panels {512,512}
//    (BLIS fixed KC=512), panels combined by single f32 adds; +bias, relu.
//  - scores: ONE ascending-e f32 FMA chain per score (K=64 single panel).
//  - top-8: thresh = 8th largest (multiplicity-counted); kept = s >= thresh.
//
// R21: score kernel was latency/barrier-bound (VALUBusy 92% summed over 4
// SIMDs = ~23%/SIMD), classic 2-phase stall. Now: double-buffered LDS tiles
// Ks[2][8][512] staged with async global_load_lds (width 16), 1 barrier per
// tile, compute overlaps next-tile loads (m97 pattern). Readlane amortized
// to 8 FMAs per broadcast. FMA chain per score still ascends e 0..63 with
// fmaf -> bit-exact.

#define B_ 8
#define L_ 1024
#define S_ 1024
#define D_ 1024
#define H_ 16
#define E_ 64
#define TOPK_ 8

__device__ __forceinline__ void gload_lds16(const float* g, float* l) {
  __builtin_amdgcn_global_load_lds(
      (const __attribute__((address_space(1))) unsigned int*)g,
      (__attribute__((address_space(3))) unsigned int*)l, 16, 0, 0);
}

// ---------------------------------------------------------------------------
// C = A(MxK,row) * B(NxK,row)^T + bias, optional relu. f32; ascending-k FMA
// chain within BLIS panels {512,512} (flush after k-tiles 31, 63), f32 adds
// across panels. (Bit-exact - do not reorder.)
// ---------------------------------------------------------------------------
template <int RELU>
__global__ __launch_bounds__(256) void gemm_abt(
    const float* __restrict__ A, const float* __restrict__ Bm,
    const float* __restrict__ bias, float* __restrict__ C,
    int M, int N, int K, int lda, int ldb, int ldc) {
  __shared__ float As[16][68];
  __shared__ float Bs[16][68];

  const int t = threadIdx.x;
  const int tx = t & 15, ty = t >> 4;
  const int m0 = blockIdx.y * 64, n0 = blockIdx.x * 64;

  float acc[4][4], tot[4][4];
#pragma unroll
  for (int r = 0; r < 4; ++r)
#pragma unroll
    for (int c = 0; c < 4; ++c) {
      acc[r][c] = 0.0f;
      tot[r][c] = 0.0f;
    }

  const int ntiles = K / 16;
  for (int ti = 0; ti < ntiles; ++ti) {
    const int kt = ti * 16;
    __syncthreads();
#pragma unroll
    for (int i = 0; i < 4; ++i) {
      const int idx = t + 256 * i;
      const int r = idx >> 4, kk = idx & 15;
      As[kk][r] = A[(long long)(m0 + r) * lda + kt + kk];
      Bs[kk][r] = Bm[(long long)(n0 + r) * ldb + kt + kk];
    }
    __syncthreads();
#pragma unroll
    for (int kk = 0; kk < 16; ++kk) {
      const float4 a4 = *reinterpret_cast<const float4*>(&As[kk][ty * 4]);
      const float4 b4 = *reinterpret_cast<const float4*>(&Bs[kk][tx * 4]);
      const float av[4] = {a4.x, a4.y, a4.z, a4.w};
      const float bv[4] = {b4.x, b4.y, b4.z, b4.w};
#pragma unroll
      for (int r = 0; r < 4; ++r)
#pragma unroll
        for (int c = 0; c < 4; ++c) acc[r][c] = fmaf(av[r], bv[c], acc[r][c]);
    }
    const bool flush =
        (K == 1024) ? (ti == 31 || ti == 63) : (ti == ntiles - 1);
    if (flush) {
#pragma unroll
      for (int r = 0; r < 4; ++r)
#pragma unroll
        for (int c = 0; c < 4; ++c) {
          tot[r][c] = __fadd_rn(tot[r][c], acc[r][c]);
          acc[r][c] = 0.0f;
        }
    }
  }

#pragma unroll
  for (int r = 0; r < 4; ++r) {
    const int m = m0 + ty * 4 + r;
#pragma unroll
    for (int c = 0; c < 4; ++c) {
      const int n = n0 + tx * 4 + c;
      float v = tot[r][c];
      if (bias) v = __fadd_rn(v, bias[n]);
      if (RELU) v = fmaxf(v, 0.0f);
      C[(long long)m * ldc + n] = v;
    }
  }
}

// ---------------------------------------------------------------------------
// Transpose K head-slices: Kt[(b*16+h)*64 + e][s] = Kf[(b*1024+s)][h*64+e].
// ---------------------------------------------------------------------------
__global__ __launch_bounds__(256) void transpose_k(const float* __restrict__ Kf,
                                                   float* __restrict__ Kt) {
  __shared__ float tl[64][65];
  const int bh = blockIdx.y;
  const int b = bh >> 4, h = bh & 15;
  const int s0 = blockIdx.x * 64;
  const int t = threadIdx.x;
#pragma unroll
  for (int i = 0; i < 16; ++i) {
    const int idx = i * 256 + t;
    const int sr = idx >> 6, e = idx & 63;
    tl[sr][e] = Kf[(((long long)(b << 10) + s0 + sr) << 10) + (h << 6) + e];
  }
  __syncthreads();
#pragma unroll
  for (int i = 0; i < 16; ++i) {
    const int idx = i * 256 + t;
    const int er = idx >> 6, s = idx & 63;
    Kt[(((long long)(bh << 6) + er) << 10) + s0 + s] = tl[s][er];
  }
}

// ---------------------------------------------------------------------------
// Fused scores + top-8 + softmax, double-buffered. Block = 256 threads =
// 4 waves x 4 rows (16 rows, same b,h). Tiles: (eo 0..7) x (ch 0..1) of
// Ks[8 e][512 cols]; buffer = ch. Per tile: issue async stage of next tile,
// compute 8 els x (readlane + 8 FMA x 4 rows), 1 barrier. acc[4][16] in
// registers; e ascends 0..63 per score -> bit-exact fmaf chain.
// ---------------------------------------------------------------------------
__global__ __launch_bounds__(256, 4) void score_topk_fused(
    const float* __restrict__ Qf, const float* __restrict__ Kt,
    float* __restrict__ A, int* __restrict__ outIdx,
    float* __restrict__ outW, int* __restrict__ outCnt) {
#pragma clang fp contract(off)
  __shared__ float Ks[2][8][512];

  const int t = threadIdx.x;
  const int wv = t >> 6, u = t & 63;
  const int row0 = blockIdx.x * 16;  // 16 consecutive rows, same (b,h)
  const int b = row0 >> 14, h = (row0 >> 10) & 15;
  const int bh = (b << 4) + h;
  const int rbase = (row0 & 1023) + wv * 4;

  float qreg[4];
#pragma unroll
  for (int r = 0; r < 4; ++r)
    qreg[r] = Qf[(((long long)(b << 10) + rbase + r) << 10) + (h << 6) + u];

  const float* KtBase = Kt + ((long long)(bh << 6) << 10);  // [64][1024]

  float acc[4][16];
#pragma unroll
  for (int r = 0; r < 4; ++r)
#pragma unroll
    for (int j = 0; j < 16; ++j) acc[r][j] = 0.0f;

  // stage tile (eo, ch) into buffer buf: rows eo*8..+7, cols ch*512..+511.
  // wave wv stages rows wv*2, wv*2+1 (2 x 1KB segments each, lane x 16B).
  auto stage = [&](int buf, int eo, int ch) {
    const int r0 = wv * 2;
#pragma unroll
    for (int i = 0; i < 2; ++i) {
      const float* src =
          KtBase + ((long long)(eo * 8 + r0 + i) << 10) + ch * 512;
      float* dst = &Ks[buf][r0 + i][0];
      gload_lds16(src + 4 * u, dst);
      gload_lds16(src + 256 + 4 * u, dst + 256);
    }
  };

  stage(0, 0, 0);
  __syncthreads();  // tile (0,0) resident

  for (int eo = 0; eo < 8; ++eo) {
    {  // ch = 0, buffer 0, acc chunks 0..7
      stage(1, eo, 1);
#pragma unroll
      for (int el = 0; el < 8; ++el) {
        const float4 k0 = *reinterpret_cast<const float4*>(&Ks[0][el][4 * u]);
        const float4 k1 =
            *reinterpret_cast<const float4*>(&Ks[0][el][256 + 4 * u]);
        const int e = eo * 8 + el;
#pragma unroll
        for (int r = 0; r < 4; ++r) {
          const float qv = __uint_as_float(
              __builtin_amdgcn_readlane(__float_as_uint(qreg[r]), e));
          acc[r][0] = fmaf(qv, k0.x, acc[r][0]);
          acc[r][1] = fmaf(qv, k0.y, acc[r][1]);
          acc[r][2] = fmaf(qv, k0.z, acc[r][2]);
          acc[r][3] = fmaf(qv, k0.w, acc[r][3]);
          acc[r][4] = fmaf(qv, k1.x, acc[r][4]);
          acc[r][5] = fmaf(qv, k1.y, acc[r][5]);
          acc[r][6] = fmaf(qv, k1.z, acc[r][6]);
          acc[r][7] = fmaf(qv, k1.w, acc[r][7]);
        }
      }
      __syncthreads();  // next tile resident; all waves done with buf0
    }
    {  // ch = 1, buffer 1, acc chunks 8..15
      if (eo < 7) stage(0, eo + 1, 0);
#pragma unroll
      for (int el = 0; el < 8; ++el) {
        const float4 k0 = *reinterpret_cast<const float4*>(&Ks[1][el][4 * u]);
        const float4 k1 =
            *reinterpret_cast<const float4*>(&Ks[1][el][256 + 4 * u]);
        const int e = eo * 8 + el;
#pragma unroll
        for (int r = 0; r < 4; ++r) {
          const float qv = __uint_as_float(
              __builtin_amdgcn_readlane(__float_as_uint(qreg[r]), e));
          acc[r][8] = fmaf(qv, k0.x, acc[r][8]);
          acc[r][9] = fmaf(qv, k0.y, acc[r][9]);
          acc[r][10] = fmaf(qv, k0.z, acc[r][10]);
          acc[r][11] = fmaf(qv, k0.w, acc[r][11]);
          acc[r][12] = fmaf(qv, k1.x, acc[r][12]);
          acc[r][13] = fmaf(qv, k1.y, acc[r][13]);
          acc[r][14] = fmaf(qv, k1.z, acc[r][14]);
          acc[r][15] = fmaf(qv, k1.w, acc[r][15]);
        }
      }
      __syncthreads();
    }
  }

  // acc chunk c (0..3) covers cols c*256 + 4u .. +3:
  //   chunks 0,1 = cols 0..511 (ch0 halves), 2,3 -> wait: mapping below.
  // Actual mapping: acc[r][0..3] = cols 4u..4u+3 (block 0), [4..7] = 256+4u
  // (block 1), [8..11] = 512+4u (block 2), [12..15] = 768+4u (block 3).

  // ---- per-row top-8 + softmax + write (r unrolled: static indexing) ----
#pragma unroll
  for (int r = 0; r < 4; ++r) {
    float s[16];
#pragma unroll
    for (int j = 0; j < 16; ++j) s[j] = acc[r][j];

    unsigned act = 0xFFFFu;
    float rowmax = 0.f, thresh = 0.f;
    for (int it = 0; it < TOPK_; ++it) {
      float lm = -INFINITY;
#pragma unroll
      for (int j = 0; j < 16; ++j)
        if (act & (1u << j)) lm = fmaxf(lm, s[j]);
      float m = lm;
#pragma unroll
      for (int d = 1; d < 64; d <<= 1) m = fmaxf(m, __shfl_xor(m, d));
      if (it == 0) rowmax = m;
      thresh = m;
      const bool has = (lm == m);
      const unsigned long long msk = __ballot(has);
      const int owner = __ffsll((long long)msk) - 1;
      if (u == owner) {
        bool done = false;
#pragma unroll
        for (int j = 0; j < 16; ++j) {
          if (!done && (act & (1u << j)) && s[j] == m) {
            act &= ~(1u << j);
            done = true;
          }
        }
      }
    }

    float zsum = 0.f;
#pragma unroll
    for (int j = 0; j < 16; ++j) {
      const bool kept = (s[j] >= thresh);
      const float e = kept ? expf((s[j] - rowmax) * 0.125f) : 0.0f;
      acc[r][j] = e;
      zsum += e;
    }
#pragma unroll
    for (int d = 1; d < 64; d <<= 1) zsum += __shfl_xor(zsum, d);
    const float inv = 1.0f / zsum;

    const long long row = row0 + wv * 4 + r;
    float* a = A + (row << 10);
    int cnt = 0;
#pragma unroll
    for (int j = 0; j < 16; ++j) {
      const bool kept = (s[j] >= thresh);
      const float w = acc[r][j] * inv;
      acc[r][j] = kept ? w : 0.0f;
      const unsigned long long mk = __ballot(kept);
      if (kept) {
        const int pos = cnt + __popcll(mk & ((1ull << u) - 1ull));
        if (pos < 16) {
          const int col = (j >> 2) * 256 + 4 * u + (j & 3);
          outIdx[row * 16 + pos] = col;
          outW[row * 16 + pos] = w;
        }
      }
      cnt += __popcll(mk);
    }
    if (u == 0) outCnt[row] = cnt < 16 ? cnt : 16;

#pragma unroll
    for (int blkc = 0; blkc < 4; ++blkc) {
      float4 o;
      o.x = acc[r][blkc * 4 + 0];
      o.y = acc[r][blkc * 4 + 1];
      o.z = acc[r][blkc * 4 + 2];
      o.w = acc[r][blkc * 4 + 3];
      *reinterpret_cast<float4*>(&a[blkc * 256 + 4 * u]) = o;
    }
  }
}

// ---------------------------------------------------------------------------
// Sparse A*v from compact lists. One wave per row (lane = e).
// ---------------------------------------------------------------------------
__global__ __launch_bounds__(256) void vagg_kernel(
    const int* __restrict__ idx, const float* __restrict__ w,
    const int* __restrict__ cnt, const float* __restrict__ Vp,
    float* __restrict__ Vagg) {
  const int wave = threadIdx.x >> 6;
  const int lane = threadIdx.x & 63;
  const long long row = (long long)blockIdx.x * 4 + wave;
  const int b = (int)(row >> 14);
  const int h = (int)((row >> 10) & 15);
  const int l = (int)(row & 1023);
  const int n = cnt[row];
  float acc = 0.0f;
  for (int i = 0; i < n; ++i) {
    const int sI = idx[row * 16 + i];
    const float ww = w[row * 16 + i];
    acc += ww * Vp[((long long)((b << 10) + sI) << 10) + (h << 6) + lane];
  }
  Vagg[((long long)((b << 10) + l) << 10) + (h << 6) + lane] = acc;
}

extern "C" void kernel_launch(void* const* d_in, const int* in_sizes, int n_in,
                              void* d_out, int out_size, void* d_ws,
                              size_t ws_size, hipStream_t stream) {
  const float* queries = (const float*)d_in[0];
  const float* keys = (const float*)d_in[1];
  const float* values = (const float*)d_in[2];
  const float* Wq = (const float*)d_in[3];
  const float* bq = (const float*)d_in[4];
  const float* Wk = (const float*)d_in[5];
  const float* bk = (const float*)d_in[6];
  const float* Wv = (const float*)d_in[7];
  const float* bv = (const float*)d_in[8];
  const float* Wo = (const float*)d_in[9];
  const float* bo = (const float*)d_in[10];

  float* out = (float*)d_out;                   // [B,L,D]
  float* Aout = out + (long long)B_ * L_ * D_;  // [B,H,L,S]

  char* ws = (char*)d_ws;
  const size_t MD = (size_t)B_ * L_ * D_ * sizeof(float);  // 33.55 MB
  const size_t NL = (size_t)B_ * H_ * L_;                   // 131072 rows
  float* Qf = (float*)ws;
  float* Kf = (float*)(ws + MD);
  float* Kt = (float*)(ws + 2 * MD);
  int* tIdx = (int*)(ws + 3 * MD);
  float* tW = (float*)(ws + 3 * MD + NL * 16 * 4);
  int* tCnt = (int*)(ws + 3 * MD + NL * 16 * 8);
  float* Vb = (float*)(ws + 3 * MD + NL * 16 * 8 + NL * 4);
  float* Vagg = Kt;  // Kt dead after score_topk_fused

  const dim3 blk(256);
  const int M = B_ * L_;  // 8192

  // Q = relu(queries @ Wq^T + bq)   [bit-exact chain]
  gemm_abt<1><<<dim3(16, M / 64), blk, 0, stream>>>(queries, Wq, bq, Qf, M, D_,
                                                    D_, D_, D_, D_);
  // K = keys @ Wk^T + bk            [bit-exact chain]
  gemm_abt<0><<<dim3(16, M / 64), blk, 0, stream>>>(keys, Wk, bk, Kf, M, D_,
                                                    D_, D_, D_, D_);
  // Kt[b,h,e,s] = Kf[b,s,h,e]
  transpose_k<<<dim3(16, B_ * H_), blk, 0, stream>>>(Kf, Kt);

  // fused scores + top-8 + softmax -> A + compact lists
  score_topk_fused<<<(int)(NL / 16), blk, 0, stream>>>(Qf, Kt, Aout, tIdx, tW,
                                                       tCnt);

  // V = relu(values @ Wv^T + bv)
  gemm_abt<1><<<dim3(16, M / 64), blk, 0, stream>>>(values, Wv, bv, Vb, M, D_,
                                                    D_, D_, D_, D_);

  // Vagg[b,l,h,:] = sum_s A * v   (writes into Kt slot)
  vagg_kernel<<<(int)(NL / 4), blk, 0, stream>>>(tIdx, tW, tCnt, Vb, Vagg);

  // out = Vagg @ Wo^T + bo
  gemm_abt<0><<<dim3(16, M / 64), blk, 0, stream>>>(Vagg, Wo, bo, out, M, D_,
                                                    D_, D_, D_, D_);
}

// Round 22
// 1570.644 us; speedup vs baseline: 1.2411x; 1.0351x over previous
//
#include <hip/hip_runtime.h>
#include <hip/hip_bf16.h>

// Shapes: B=8, L=S=1024, D=1024, H=16, E=64, TOP_K=8.
// d_out = [ out (B*L*D f32) | A (B*H*L*S f32) ]
//
// PASSING reference model (R16, keep bit-exact):
//  - projections: ascending-k f32 FMA chain within K-panels {512,512}
//    (BLIS fixed KC=512), panels combined by single f32 adds; +bias, relu.
//  - scores: ONE ascending-e f32 FMA chain per score (K=64 single panel).
//  - top-8: thresh = 8th largest (multiplicity-counted); kept = s >= thresh.
//
// R22: epilogue rework. (1) DPP wave reduces (no LDS ds_bpermute): umax on
// ordered uints + identity-0 sums -> OOB-safe. (2) Ownerless top-8 via
// descending-threshold extraction (exact incl. ties), 4 rows interleaved.
// (3) readlane hoist shared across ch phases. (4) GEMM reg-prefetch dbuf.

#define B_ 8
#define L_ 1024
#define S_ 1024
#define D_ 1024
#define H_ 16
#define E_ 64
#define TOPK_ 8

__device__ __forceinline__ void gload_lds16(const float* g, float* l) {
  __builtin_amdgcn_global_load_lds(
      (const __attribute__((address_space(1))) unsigned int*)g,
      (__attribute__((address_space(3))) unsigned int*)l, 16, 0, 0);
}

// float -> orderable uint (monotone bijection)
__device__ __forceinline__ unsigned enc_ord(float f) {
  int s = __float_as_int(f);
  return (unsigned)(s ^ ((s >> 31) | 0x80000000));
}
__device__ __forceinline__ float dec_ord(unsigned u) {
  int m = ((int)u >= 0) ? 0xFFFFFFFF : 0x80000000;
  return __int_as_float((int)(u ^ (unsigned)m));
}

// wave64 max of ordered uints via DPP (row_shr + row_bcast), result uniform.
// umax identity is 0, so either OOB semantic (old or 0) is safe.
__device__ __forceinline__ unsigned dpp_umax64(unsigned x) {
  unsigned t;
  t = (unsigned)__builtin_amdgcn_update_dpp((int)x, (int)x, 0x111, 0xf, 0xf, false);
  x = x > t ? x : t;
  t = (unsigned)__builtin_amdgcn_update_dpp((int)x, (int)x, 0x112, 0xf, 0xf, false);
  x = x > t ? x : t;
  t = (unsigned)__builtin_amdgcn_update_dpp((int)x, (int)x, 0x114, 0xf, 0xf, false);
  x = x > t ? x : t;
  t = (unsigned)__builtin_amdgcn_update_dpp((int)x, (int)x, 0x118, 0xf, 0xf, false);
  x = x > t ? x : t;
  t = (unsigned)__builtin_amdgcn_update_dpp((int)x, (int)x, 0x142, 0xa, 0xf, false);
  x = x > t ? x : t;
  t = (unsigned)__builtin_amdgcn_update_dpp((int)x, (int)x, 0x143, 0xc, 0xf, false);
  x = x > t ? x : t;
  return (unsigned)__builtin_amdgcn_readlane((int)x, 63);
}

// wave64 float sum via DPP (identity 0 either way), result uniform.
__device__ __forceinline__ float dpp_fsum64(float x) {
  float t;
  t = __int_as_float(__builtin_amdgcn_update_dpp(0, __float_as_int(x), 0x111, 0xf, 0xf, true));
  x += t;
  t = __int_as_float(__builtin_amdgcn_update_dpp(0, __float_as_int(x), 0x112, 0xf, 0xf, true));
  x += t;
  t = __int_as_float(__builtin_amdgcn_update_dpp(0, __float_as_int(x), 0x114, 0xf, 0xf, true));
  x += t;
  t = __int_as_float(__builtin_amdgcn_update_dpp(0, __float_as_int(x), 0x118, 0xf, 0xf, true));
  x += t;
  t = __int_as_float(__builtin_amdgcn_update_dpp(0, __float_as_int(x), 0x142, 0xa, 0xf, true));
  x += t;
  t = __int_as_float(__builtin_amdgcn_update_dpp(0, __float_as_int(x), 0x143, 0xc, 0xf, true));
  x += t;
  return __int_as_float(__builtin_amdgcn_readlane(__float_as_int(x), 63));
}

// ---------------------------------------------------------------------------
// C = A(MxK,row) * B(NxK,row)^T + bias, optional relu. f32; ascending-k FMA
// chain within BLIS panels {512,512} (flush after k-tiles 31, 63), f32 adds
// across panels. Reg-prefetch double-buffered staging. (Bit-exact chain.)
// ---------------------------------------------------------------------------
template <int RELU>
__global__ __launch_bounds__(256) void gemm_abt(
    const float* __restrict__ A, const float* __restrict__ Bm,
    const float* __restrict__ bias, float* __restrict__ C,
    int M, int N, int K, int lda, int ldb, int ldc) {
  __shared__ float As[16][68];
  __shared__ float Bs[16][68];

  const int t = threadIdx.x;
  const int tx = t & 15, ty = t >> 4;
  const int m0 = blockIdx.y * 64, n0 = blockIdx.x * 64;

  float acc[4][4], tot[4][4];
#pragma unroll
  for (int r = 0; r < 4; ++r)
#pragma unroll
    for (int c = 0; c < 4; ++c) {
      acc[r][c] = 0.0f;
      tot[r][c] = 0.0f;
    }

  float pa[4], pb[4];
#pragma unroll
  for (int i = 0; i < 4; ++i) {
    const int idx = t + 256 * i;
    const int r = idx >> 4, kk = idx & 15;
    pa[i] = A[(long long)(m0 + r) * lda + kk];
    pb[i] = Bm[(long long)(n0 + r) * ldb + kk];
  }

  const int ntiles = K / 16;
  for (int ti = 0; ti < ntiles; ++ti) {
    __syncthreads();
#pragma unroll
    for (int i = 0; i < 4; ++i) {
      const int idx = t + 256 * i;
      const int r = idx >> 4, kk = idx & 15;
      As[kk][r] = pa[i];
      Bs[kk][r] = pb[i];
    }
    __syncthreads();
    if (ti + 1 < ntiles) {
      const int kt = (ti + 1) * 16;
#pragma unroll
      for (int i = 0; i < 4; ++i) {
        const int idx = t + 256 * i;
        const int r = idx >> 4, kk = idx & 15;
        pa[i] = A[(long long)(m0 + r) * lda + kt + kk];
        pb[i] = Bm[(long long)(n0 + r) * ldb + kt + kk];
      }
    }
#pragma unroll
    for (int kk = 0; kk < 16; ++kk) {
      const float4 a4 = *reinterpret_cast<const float4*>(&As[kk][ty * 4]);
      const float4 b4 = *reinterpret_cast<const float4*>(&Bs[kk][tx * 4]);
      const float av[4] = {a4.x, a4.y, a4.z, a4.w};
      const float bv[4] = {b4.x, b4.y, b4.z, b4.w};
#pragma unroll
      for (int r = 0; r < 4; ++r)
#pragma unroll
        for (int c = 0; c < 4; ++c) acc[r][c] = fmaf(av[r], bv[c], acc[r][c]);
    }
    const bool flush =
        (K == 1024) ? (ti == 31 || ti == 63) : (ti == ntiles - 1);
    if (flush) {
#pragma unroll
      for (int r = 0; r < 4; ++r)
#pragma unroll
        for (int c = 0; c < 4; ++c) {
          tot[r][c] = __fadd_rn(tot[r][c], acc[r][c]);
          acc[r][c] = 0.0f;
        }
    }
  }

#pragma unroll
  for (int r = 0; r < 4; ++r) {
    const int m = m0 + ty * 4 + r;
#pragma unroll
    for (int c = 0; c < 4; ++c) {
      const int n = n0 + tx * 4 + c;
      float v = tot[r][c];
      if (bias) v = __fadd_rn(v, bias[n]);
      if (RELU) v = fmaxf(v, 0.0f);
      C[(long long)m * ldc + n] = v;
    }
  }
}

// ---------------------------------------------------------------------------
// Transpose K head-slices: Kt[(b*16+h)*64 + e][s] = Kf[(b*1024+s)][h*64+e].
// ---------------------------------------------------------------------------
__global__ __launch_bounds__(256) void transpose_k(const float* __restrict__ Kf,
                                                   float* __restrict__ Kt) {
  __shared__ float tl[64][65];
  const int bh = blockIdx.y;
  const int b = bh >> 4, h = bh & 15;
  const int s0 = blockIdx.x * 64;
  const int t = threadIdx.x;
#pragma unroll
  for (int i = 0; i < 16; ++i) {
    const int idx = i * 256 + t;
    const int sr = idx >> 6, e = idx & 63;
    tl[sr][e] = Kf[(((long long)(b << 10) + s0 + sr) << 10) + (h << 6) + e];
  }
  __syncthreads();
#pragma unroll
  for (int i = 0; i < 16; ++i) {
    const int idx = i * 256 + t;
    const int er = idx >> 6, s = idx & 63;
    Kt[(((long long)(bh << 6) + er) << 10) + s0 + s] = tl[s][er];
  }
}

// ---------------------------------------------------------------------------
// Fused scores + top-8 + softmax, double-buffered async staging.
// Block = 256 = 4 waves x 4 rows. acc[4][16] in regs; e ascends 0..63 per
// score -> bit-exact fmaf chain. Top-8 per row via descending-threshold
// extraction (exact incl. tie multiplicity), DPP reduces, 4 rows
// interleaved. qv broadcasts hoisted per eo (shared by both ch phases).
// ---------------------------------------------------------------------------
__global__ __launch_bounds__(256, 4) void score_topk_fused(
    const float* __restrict__ Qf, const float* __restrict__ Kt,
    float* __restrict__ A, int* __restrict__ outIdx,
    float* __restrict__ outW, int* __restrict__ outCnt) {
#pragma clang fp contract(off)
  __shared__ float Ks[2][8][512];

  const int t = threadIdx.x;
  const int wv = t >> 6, u = t & 63;
  const int row0 = blockIdx.x * 16;  // 16 consecutive rows, same (b,h)
  const int b = row0 >> 14, h = (row0 >> 10) & 15;
  const int bh = (b << 4) + h;
  const int rbase = (row0 & 1023) + wv * 4;

  float qreg[4];
#pragma unroll
  for (int r = 0; r < 4; ++r)
    qreg[r] = Qf[(((long long)(b << 10) + rbase + r) << 10) + (h << 6) + u];

  const float* KtBase = Kt + ((long long)(bh << 6) << 10);  // [64][1024]

  float acc[4][16];
#pragma unroll
  for (int r = 0; r < 4; ++r)
#pragma unroll
    for (int j = 0; j < 16; ++j) acc[r][j] = 0.0f;

  auto stage = [&](int buf, int eo, int ch) {
    const int r0 = wv * 2;
#pragma unroll
    for (int i = 0; i < 2; ++i) {
      const float* src =
          KtBase + ((long long)(eo * 8 + r0 + i) << 10) + ch * 512;
      float* dst = &Ks[buf][r0 + i][0];
      gload_lds16(src + 4 * u, dst);
      gload_lds16(src + 256 + 4 * u, dst + 256);
    }
  };

  stage(0, 0, 0);
  __syncthreads();  // tile (0,0) resident

  for (int eo = 0; eo < 8; ++eo) {
    // hoist q broadcasts for this eo (shared by ch0 and ch1)
    float qv[8][4];
#pragma unroll
    for (int el = 0; el < 8; ++el)
#pragma unroll
      for (int r = 0; r < 4; ++r)
        qv[el][r] = __uint_as_float(__builtin_amdgcn_readlane(
            __float_as_uint(qreg[r]), eo * 8 + el));

    {  // ch = 0, buffer 0, acc chunks 0..7
      stage(1, eo, 1);
#pragma unroll
      for (int el = 0; el < 8; ++el) {
        const float4 k0 = *reinterpret_cast<const float4*>(&Ks[0][el][4 * u]);
        const float4 k1 =
            *reinterpret_cast<const float4*>(&Ks[0][el][256 + 4 * u]);
#pragma unroll
        for (int r = 0; r < 4; ++r) {
          const float q = qv[el][r];
          acc[r][0] = fmaf(q, k0.x, acc[r][0]);
          acc[r][1] = fmaf(q, k0.y, acc[r][1]);
          acc[r][2] = fmaf(q, k0.z, acc[r][2]);
          acc[r][3] = fmaf(q, k0.w, acc[r][3]);
          acc[r][4] = fmaf(q, k1.x, acc[r][4]);
          acc[r][5] = fmaf(q, k1.y, acc[r][5]);
          acc[r][6] = fmaf(q, k1.z, acc[r][6]);
          acc[r][7] = fmaf(q, k1.w, acc[r][7]);
        }
      }
      __syncthreads();
    }
    {  // ch = 1, buffer 1, acc chunks 8..15
      if (eo < 7) stage(0, eo + 1, 0);
#pragma unroll
      for (int el = 0; el < 8; ++el) {
        const float4 k0 = *reinterpret_cast<const float4*>(&Ks[1][el][4 * u]);
        const float4 k1 =
            *reinterpret_cast<const float4*>(&Ks[1][el][256 + 4 * u]);
#pragma unroll
        for (int r = 0; r < 4; ++r) {
          const float q = qv[el][r];
          acc[r][8] = fmaf(q, k0.x, acc[r][8]);
          acc[r][9] = fmaf(q, k0.y, acc[r][9]);
          acc[r][10] = fmaf(q, k0.z, acc[r][10]);
          acc[r][11] = fmaf(q, k0.w, acc[r][11]);
          acc[r][12] = fmaf(q, k1.x, acc[r][12]);
          acc[r][13] = fmaf(q, k1.y, acc[r][13]);
          acc[r][14] = fmaf(q, k1.z, acc[r][14]);
          acc[r][15] = fmaf(q, k1.w, acc[r][15]);
        }
      }
      __syncthreads();
    }
  }
  // acc[r][blkc*4+q] = col blkc*256 + 4u + q.

  // ---- top-8 thresholds, 4 rows interleaved, descending extraction ----
  float T[4], cnt8[4], rowmax[4];
#pragma unroll
  for (int r = 0; r < 4; ++r) {
    T[r] = INFINITY;
    cnt8[r] = 0.0f;
    rowmax[r] = 0.0f;
  }

  for (int it = 0; it < TOPK_; ++it) {
    float m[4];
#pragma unroll
    for (int r = 0; r < 4; ++r) {
      float lm = -INFINITY;
#pragma unroll
      for (int j = 0; j < 16; ++j) {
        const float v = acc[r][j];
        lm = fmaxf(lm, v < T[r] ? v : -INFINITY);
      }
      m[r] = lm;
    }
    unsigned mu[4];
#pragma unroll
    for (int r = 0; r < 4; ++r) mu[r] = enc_ord(m[r]);
#pragma unroll
    for (int r = 0; r < 4; ++r) mu[r] = dpp_umax64(mu[r]);
#pragma unroll
    for (int r = 0; r < 4; ++r) m[r] = dec_ord(mu[r]);

    float nn[4];
#pragma unroll
    for (int r = 0; r < 4; ++r) {
      float cl = 0.0f;
#pragma unroll
      for (int j = 0; j < 16; ++j) cl += (acc[r][j] == m[r]) ? 1.0f : 0.0f;
      nn[r] = cl;
    }
#pragma unroll
    for (int r = 0; r < 4; ++r) nn[r] = dpp_fsum64(nn[r]);

#pragma unroll
    for (int r = 0; r < 4; ++r) {
      if (it == 0) rowmax[r] = m[r];
      const bool upd = (cnt8[r] < 8.0f);
      T[r] = upd ? m[r] : T[r];
      cnt8[r] = upd ? cnt8[r] + nn[r] : cnt8[r];
    }
  }

  // ---- softmax + masked write + compact lists (per row) ----
#pragma unroll
  for (int r = 0; r < 4; ++r) {
    const float thresh = T[r];
    float e16[16];
    float zl = 0.0f;
#pragma unroll
    for (int j = 0; j < 16; ++j) {
      const bool kept = (acc[r][j] >= thresh);
      const float e = kept ? __expf((acc[r][j] - rowmax[r]) * 0.125f) : 0.0f;
      e16[j] = e;
      zl += e;
    }
    const float zsum = dpp_fsum64(zl);
    const float inv = 1.0f / zsum;

    const long long row = row0 + wv * 4 + r;
    float* a = A + (row << 10);
    int cnt = 0;
#pragma unroll
    for (int j = 0; j < 16; ++j) {
      const bool kept = (acc[r][j] >= thresh);
      const float w = e16[j] * inv;
      e16[j] = kept ? w : 0.0f;
      const unsigned long long mk = __ballot(kept);
      if (kept) {
        const int pos = cnt + __popcll(mk & ((1ull << u) - 1ull));
        if (pos < 16) {
          const int col = (j >> 2) * 256 + 4 * u + (j & 3);
          outIdx[row * 16 + pos] = col;
          outW[row * 16 + pos] = w;
        }
      }
      cnt += __popcll(mk);
    }
    if (u == 0) outCnt[row] = cnt < 16 ? cnt : 16;

#pragma unroll
    for (int blkc = 0; blkc < 4; ++blkc) {
      float4 o;
      o.x = e16[blkc * 4 + 0];
      o.y = e16[blkc * 4 + 1];
      o.z = e16[blkc * 4 + 2];
      o.w = e16[blkc * 4 + 3];
      *reinterpret_cast<float4*>(&a[blkc * 256 + 4 * u]) = o;
    }
  }
}

// ---------------------------------------------------------------------------
// Sparse A*v from compact lists. One wave per row (lane = e).
// ---------------------------------------------------------------------------
__global__ __launch_bounds__(256) void vagg_kernel(
    const int* __restrict__ idx, const float* __restrict__ w,
    const int* __restrict__ cnt, const float* __restrict__ Vp,
    float* __restrict__ Vagg) {
  const int wave = threadIdx.x >> 6;
  const int lane = threadIdx.x & 63;
  const long long row = (long long)blockIdx.x * 4 + wave;
  const int b = (int)(row >> 14);
  const int h = (int)((row >> 10) & 15);
  const int l = (int)(row & 1023);
  const int n = cnt[row];
  float acc = 0.0f;
  for (int i = 0; i < n; ++i) {
    const int sI = idx[row * 16 + i];
    const float ww = w[row * 16 + i];
    acc += ww * Vp[((long long)((b << 10) + sI) << 10) + (h << 6) + lane];
  }
  Vagg[((long long)((b << 10) + l) << 10) + (h << 6) + lane] = acc;
}

extern "C" void kernel_launch(void* const* d_in, const int* in_sizes, int n_in,
                              void* d_out, int out_size, void* d_ws,
                              size_t ws_size, hipStream_t stream) {
  const float* queries = (const float*)d_in[0];
  const float* keys = (const float*)d_in[1];
  const float* values = (const float*)d_in[2];
  const float* Wq = (const float*)d_in[3];
  const float* bq = (const float*)d_in[4];
  const float* Wk = (const float*)d_in[5];
  const float* bk = (const float*)d_in[6];
  const float* Wv = (const float*)d_in[7];
  const float* bv = (const float*)d_in[8];
  const float* Wo = (const float*)d_in[9];
  const float* bo = (const float*)d_in[10];

  float* out = (float*)d_out;                   // [B,L,D]
  float* Aout = out + (long long)B_ * L_ * D_;  // [B,H,L,S]

  char* ws = (char*)d_ws;
  const size_t MD = (size_t)B_ * L_ * D_ * sizeof(float);  // 33.55 MB
  const size_t NL = (size_t)B_ * H_ * L_;                   // 131072 rows
  float* Qf = (float*)ws;
  float* Kf = (float*)(ws + MD);
  float* Kt = (float*)(ws + 2 * MD);
  int* tIdx = (int*)(ws + 3 * MD);
  float* tW = (float*)(ws + 3 * MD + NL * 16 * 4);
  int* tCnt = (int*)(ws + 3 * MD + NL * 16 * 8);
  float* Vb = (float*)(ws + 3 * MD + NL * 16 * 8 + NL * 4);
  float* Vagg = Kt;  // Kt dead after score_topk_fused

  const dim3 blk(256);
  const int M = B_ * L_;  // 8192

  // Q = relu(queries @ Wq^T + bq)   [bit-exact chain]
  gemm_abt<1><<<dim3(16, M / 64), blk, 0, stream>>>(queries, Wq, bq, Qf, M, D_,
                                                    D_, D_, D_, D_);
  // K = keys @ Wk^T + bk            [bit-exact chain]
  gemm_abt<0><<<dim3(16, M / 64), blk, 0, stream>>>(keys, Wk, bk, Kf, M, D_,
                                                    D_, D_, D_, D_);
  // Kt[b,h,e,s] = Kf[b,s,h,e]
  transpose_k<<<dim3(16, B_ * H_), blk, 0, stream>>>(Kf, Kt);

  // fused scores + top-8 + softmax -> A + compact lists
  score_topk_fused<<<(int)(NL / 16), blk, 0, stream>>>(Qf, Kt, Aout, tIdx, tW,
                                                       tCnt);

  // V = relu(values @ Wv^T + bv)
  gemm_abt<1><<<dim3(16, M / 64), blk, 0, stream>>>(values, Wv, bv, Vb, M, D_,
                                                    D_, D_, D_, D_);

  // Vagg[b,l,h,:] = sum_s A * v   (writes into Kt slot)
  vagg_kernel<<<(int)(NL / 4), blk, 0, stream>>>(tIdx, tW, tCnt, Vb, Vagg);

  // out = Vagg @ Wo^T + bo
  gemm_abt<0><<<dim3(16, M / 64), blk, 0, stream>>>(Vagg, Wo, bo, out, M, D_,
                                                    D_, D_, D_, D_);
}

// Round 23
// 1560.418 us; speedup vs baseline: 1.2492x; 1.0066x over previous
//
#include <hip/hip_runtime.h>
#include <hip/hip_bf16.h>

// Shapes: B=8, L=S=1024, D=1024, H=16, E=64, TOP_K=8.
// d_out = [ out (B*L*D f32) | A (B*H*L*S f32) ]
//
// PASSING reference model (R16, keep bit-exact):
//  - projections: ascending-k f32 FMA chain within K-panels {512,512}
//    (BLIS fixed KC=512), panels combined by single f32 adds; +bias, relu.
//  - scores: ONE ascending-e f32 FMA chain per score (K=64 single panel).
//  - top-8: thresh = 8th largest (multiplicity-counted); kept = s >= thresh.
//
// R23: GEMM rework (fused score kernel unchanged from R22, verified):
// single-barrier LDS double-buffer (As/Bs[2]), vectorized dwordx4 global
// staging (1 per matrix per thread per tile), one __syncthreads per k-tile.
// FMA chain order untouched -> bit-exact.

#define B_ 8
#define L_ 1024
#define S_ 1024
#define D_ 1024
#define H_ 16
#define E_ 64
#define TOPK_ 8

__device__ __forceinline__ void gload_lds16(const float* g, float* l) {
  __builtin_amdgcn_global_load_lds(
      (const __attribute__((address_space(1))) unsigned int*)g,
      (__attribute__((address_space(3))) unsigned int*)l, 16, 0, 0);
}

// float -> orderable uint (monotone bijection)
__device__ __forceinline__ unsigned enc_ord(float f) {
  int s = __float_as_int(f);
  return (unsigned)(s ^ ((s >> 31) | 0x80000000));
}
__device__ __forceinline__ float dec_ord(unsigned u) {
  int m = ((int)u >= 0) ? 0xFFFFFFFF : 0x80000000;
  return __int_as_float((int)(u ^ (unsigned)m));
}

// wave64 max of ordered uints via DPP (row_shr + row_bcast), result uniform.
__device__ __forceinline__ unsigned dpp_umax64(unsigned x) {
  unsigned t;
  t = (unsigned)__builtin_amdgcn_update_dpp((int)x, (int)x, 0x111, 0xf, 0xf, false);
  x = x > t ? x : t;
  t = (unsigned)__builtin_amdgcn_update_dpp((int)x, (int)x, 0x112, 0xf, 0xf, false);
  x = x > t ? x : t;
  t = (unsigned)__builtin_amdgcn_update_dpp((int)x, (int)x, 0x114, 0xf, 0xf, false);
  x = x > t ? x : t;
  t = (unsigned)__builtin_amdgcn_update_dpp((int)x, (int)x, 0x118, 0xf, 0xf, false);
  x = x > t ? x : t;
  t = (unsigned)__builtin_amdgcn_update_dpp((int)x, (int)x, 0x142, 0xa, 0xf, false);
  x = x > t ? x : t;
  t = (unsigned)__builtin_amdgcn_update_dpp((int)x, (int)x, 0x143, 0xc, 0xf, false);
  x = x > t ? x : t;
  return (unsigned)__builtin_amdgcn_readlane((int)x, 63);
}

// wave64 float sum via DPP (identity 0), result uniform.
__device__ __forceinline__ float dpp_fsum64(float x) {
  float t;
  t = __int_as_float(__builtin_amdgcn_update_dpp(0, __float_as_int(x), 0x111, 0xf, 0xf, true));
  x += t;
  t = __int_as_float(__builtin_amdgcn_update_dpp(0, __float_as_int(x), 0x112, 0xf, 0xf, true));
  x += t;
  t = __int_as_float(__builtin_amdgcn_update_dpp(0, __float_as_int(x), 0x114, 0xf, 0xf, true));
  x += t;
  t = __int_as_float(__builtin_amdgcn_update_dpp(0, __float_as_int(x), 0x118, 0xf, 0xf, true));
  x += t;
  t = __int_as_float(__builtin_amdgcn_update_dpp(0, __float_as_int(x), 0x142, 0xa, 0xf, true));
  x += t;
  t = __int_as_float(__builtin_amdgcn_update_dpp(0, __float_as_int(x), 0x143, 0xc, 0xf, true));
  x += t;
  return __int_as_float(__builtin_amdgcn_readlane(__float_as_int(x), 63));
}

// ---------------------------------------------------------------------------
// C = A(MxK,row) * B(NxK,row)^T + bias, optional relu. f32; ascending-k FMA
// chain within BLIS panels {512,512} (flush after k-tiles 31, 63), f32 adds
// across panels. Single-barrier LDS double-buffer; dwordx4 staging.
// Thread t stages row r = t>>2, k-quad kq = t&3 of each matrix.
// ---------------------------------------------------------------------------
template <int RELU>
__global__ __launch_bounds__(256) void gemm_abt(
    const float* __restrict__ A, const float* __restrict__ Bm,
    const float* __restrict__ bias, float* __restrict__ C,
    int M, int N, int K, int lda, int ldb, int ldc) {
  __shared__ float As[2][16][68];
  __shared__ float Bs[2][16][68];

  const int t = threadIdx.x;
  const int tx = t & 15, ty = t >> 4;
  const int m0 = blockIdx.y * 64, n0 = blockIdx.x * 64;
  const int sr = t >> 2, skq = (t & 3) * 4;  // staging row / k-quad base

  float acc[4][4], tot[4][4];
#pragma unroll
  for (int r = 0; r < 4; ++r)
#pragma unroll
    for (int c = 0; c < 4; ++c) {
      acc[r][c] = 0.0f;
      tot[r][c] = 0.0f;
    }

  const float* Arow = A + (long long)(m0 + sr) * lda + skq;
  const float* Brow = Bm + (long long)(n0 + sr) * ldb + skq;

  float4 pa = *reinterpret_cast<const float4*>(Arow);
  float4 pb = *reinterpret_cast<const float4*>(Brow);
  {
    As[0][skq + 0][sr] = pa.x;
    As[0][skq + 1][sr] = pa.y;
    As[0][skq + 2][sr] = pa.z;
    As[0][skq + 3][sr] = pa.w;
    Bs[0][skq + 0][sr] = pb.x;
    Bs[0][skq + 1][sr] = pb.y;
    Bs[0][skq + 2][sr] = pb.z;
    Bs[0][skq + 3][sr] = pb.w;
  }
  __syncthreads();

  const int ntiles = K / 16;
  for (int ti = 0; ti < ntiles; ++ti) {
    const int cur = ti & 1, nxt = cur ^ 1;
    if (ti + 1 < ntiles) {
      pa = *reinterpret_cast<const float4*>(Arow + (ti + 1) * 16);
      pb = *reinterpret_cast<const float4*>(Brow + (ti + 1) * 16);
    }
#pragma unroll
    for (int kk = 0; kk < 16; ++kk) {
      const float4 a4 = *reinterpret_cast<const float4*>(&As[cur][kk][ty * 4]);
      const float4 b4 = *reinterpret_cast<const float4*>(&Bs[cur][kk][tx * 4]);
      const float av[4] = {a4.x, a4.y, a4.z, a4.w};
      const float bv[4] = {b4.x, b4.y, b4.z, b4.w};
#pragma unroll
      for (int r = 0; r < 4; ++r)
#pragma unroll
        for (int c = 0; c < 4; ++c) acc[r][c] = fmaf(av[r], bv[c], acc[r][c]);
    }
    if (ti + 1 < ntiles) {
      As[nxt][skq + 0][sr] = pa.x;
      As[nxt][skq + 1][sr] = pa.y;
      As[nxt][skq + 2][sr] = pa.z;
      As[nxt][skq + 3][sr] = pa.w;
      Bs[nxt][skq + 0][sr] = pb.x;
      Bs[nxt][skq + 1][sr] = pb.y;
      Bs[nxt][skq + 2][sr] = pb.z;
      Bs[nxt][skq + 3][sr] = pb.w;
    }
    const bool flush =
        (K == 1024) ? (ti == 31 || ti == 63) : (ti == ntiles - 1);
    if (flush) {
#pragma unroll
      for (int r = 0; r < 4; ++r)
#pragma unroll
        for (int c = 0; c < 4; ++c) {
          tot[r][c] = __fadd_rn(tot[r][c], acc[r][c]);
          acc[r][c] = 0.0f;
        }
    }
    __syncthreads();
  }

#pragma unroll
  for (int r = 0; r < 4; ++r) {
    const int m = m0 + ty * 4 + r;
#pragma unroll
    for (int c = 0; c < 4; ++c) {
      const int n = n0 + tx * 4 + c;
      float v = tot[r][c];
      if (bias) v = __fadd_rn(v, bias[n]);
      if (RELU) v = fmaxf(v, 0.0f);
      C[(long long)m * ldc + n] = v;
    }
  }
}

// ---------------------------------------------------------------------------
// Transpose K head-slices: Kt[(b*16+h)*64 + e][s] = Kf[(b*1024+s)][h*64+e].
// ---------------------------------------------------------------------------
__global__ __launch_bounds__(256) void transpose_k(const float* __restrict__ Kf,
                                                   float* __restrict__ Kt) {
  __shared__ float tl[64][65];
  const int bh = blockIdx.y;
  const int b = bh >> 4, h = bh & 15;
  const int s0 = blockIdx.x * 64;
  const int t = threadIdx.x;
#pragma unroll
  for (int i = 0; i < 16; ++i) {
    const int idx = i * 256 + t;
    const int sr = idx >> 6, e = idx & 63;
    tl[sr][e] = Kf[(((long long)(b << 10) + s0 + sr) << 10) + (h << 6) + e];
  }
  __syncthreads();
#pragma unroll
  for (int i = 0; i < 16; ++i) {
    const int idx = i * 256 + t;
    const int er = idx >> 6, s = idx & 63;
    Kt[(((long long)(bh << 6) + er) << 10) + s0 + s] = tl[s][er];
  }
}

// ---------------------------------------------------------------------------
// Fused scores + top-8 + softmax (unchanged from R22, verified).
// ---------------------------------------------------------------------------
__global__ __launch_bounds__(256, 4) void score_topk_fused(
    const float* __restrict__ Qf, const float* __restrict__ Kt,
    float* __restrict__ A, int* __restrict__ outIdx,
    float* __restrict__ outW, int* __restrict__ outCnt) {
#pragma clang fp contract(off)
  __shared__ float Ks[2][8][512];

  const int t = threadIdx.x;
  const int wv = t >> 6, u = t & 63;
  const int row0 = blockIdx.x * 16;
  const int b = row0 >> 14, h = (row0 >> 10) & 15;
  const int bh = (b << 4) + h;
  const int rbase = (row0 & 1023) + wv * 4;

  float qreg[4];
#pragma unroll
  for (int r = 0; r < 4; ++r)
    qreg[r] = Qf[(((long long)(b << 10) + rbase + r) << 10) + (h << 6) + u];

  const float* KtBase = Kt + ((long long)(bh << 6) << 10);  // [64][1024]

  float acc[4][16];
#pragma unroll
  for (int r = 0; r < 4; ++r)
#pragma unroll
    for (int j = 0; j < 16; ++j) acc[r][j] = 0.0f;

  auto stage = [&](int buf, int eo, int ch) {
    const int r0 = wv * 2;
#pragma unroll
    for (int i = 0; i < 2; ++i) {
      const float* src =
          KtBase + ((long long)(eo * 8 + r0 + i) << 10) + ch * 512;
      float* dst = &Ks[buf][r0 + i][0];
      gload_lds16(src + 4 * u, dst);
      gload_lds16(src + 256 + 4 * u, dst + 256);
    }
  };

  stage(0, 0, 0);
  __syncthreads();

  for (int eo = 0; eo < 8; ++eo) {
    float qv[8][4];
#pragma unroll
    for (int el = 0; el < 8; ++el)
#pragma unroll
      for (int r = 0; r < 4; ++r)
        qv[el][r] = __uint_as_float(__builtin_amdgcn_readlane(
            __float_as_uint(qreg[r]), eo * 8 + el));

    {  // ch = 0
      stage(1, eo, 1);
#pragma unroll
      for (int el = 0; el < 8; ++el) {
        const float4 k0 = *reinterpret_cast<const float4*>(&Ks[0][el][4 * u]);
        const float4 k1 =
            *reinterpret_cast<const float4*>(&Ks[0][el][256 + 4 * u]);
#pragma unroll
        for (int r = 0; r < 4; ++r) {
          const float q = qv[el][r];
          acc[r][0] = fmaf(q, k0.x, acc[r][0]);
          acc[r][1] = fmaf(q, k0.y, acc[r][1]);
          acc[r][2] = fmaf(q, k0.z, acc[r][2]);
          acc[r][3] = fmaf(q, k0.w, acc[r][3]);
          acc[r][4] = fmaf(q, k1.x, acc[r][4]);
          acc[r][5] = fmaf(q, k1.y, acc[r][5]);
          acc[r][6] = fmaf(q, k1.z, acc[r][6]);
          acc[r][7] = fmaf(q, k1.w, acc[r][7]);
        }
      }
      __syncthreads();
    }
    {  // ch = 1
      if (eo < 7) stage(0, eo + 1, 0);
#pragma unroll
      for (int el = 0; el < 8; ++el) {
        const float4 k0 = *reinterpret_cast<const float4*>(&Ks[1][el][4 * u]);
        const float4 k1 =
            *reinterpret_cast<const float4*>(&Ks[1][el][256 + 4 * u]);
#pragma unroll
        for (int r = 0; r < 4; ++r) {
          const float q = qv[el][r];
          acc[r][8] = fmaf(q, k0.x, acc[r][8]);
          acc[r][9] = fmaf(q, k0.y, acc[r][9]);
          acc[r][10] = fmaf(q, k0.z, acc[r][10]);
          acc[r][11] = fmaf(q, k0.w, acc[r][11]);
          acc[r][12] = fmaf(q, k1.x, acc[r][12]);
          acc[r][13] = fmaf(q, k1.y, acc[r][13]);
          acc[r][14] = fmaf(q, k1.z, acc[r][14]);
          acc[r][15] = fmaf(q, k1.w, acc[r][15]);
        }
      }
      __syncthreads();
    }
  }

  // ---- top-8 thresholds, 4 rows interleaved, descending extraction ----
  float T[4], cnt8[4], rowmax[4];
#pragma unroll
  for (int r = 0; r < 4; ++r) {
    T[r] = INFINITY;
    cnt8[r] = 0.0f;
    rowmax[r] = 0.0f;
  }

  for (int it = 0; it < TOPK_; ++it) {
    float m[4];
#pragma unroll
    for (int r = 0; r < 4; ++r) {
      float lm = -INFINITY;
#pragma unroll
      for (int j = 0; j < 16; ++j) {
        const float v = acc[r][j];
        lm = fmaxf(lm, v < T[r] ? v : -INFINITY);
      }
      m[r] = lm;
    }
    unsigned mu[4];
#pragma unroll
    for (int r = 0; r < 4; ++r) mu[r] = enc_ord(m[r]);
#pragma unroll
    for (int r = 0; r < 4; ++r) mu[r] = dpp_umax64(mu[r]);
#pragma unroll
    for (int r = 0; r < 4; ++r) m[r] = dec_ord(mu[r]);

    float nn[4];
#pragma unroll
    for (int r = 0; r < 4; ++r) {
      float cl = 0.0f;
#pragma unroll
      for (int j = 0; j < 16; ++j) cl += (acc[r][j] == m[r]) ? 1.0f : 0.0f;
      nn[r] = cl;
    }
#pragma unroll
    for (int r = 0; r < 4; ++r) nn[r] = dpp_fsum64(nn[r]);

#pragma unroll
    for (int r = 0; r < 4; ++r) {
      if (it == 0) rowmax[r] = m[r];
      const bool upd = (cnt8[r] < 8.0f);
      T[r] = upd ? m[r] : T[r];
      cnt8[r] = upd ? cnt8[r] + nn[r] : cnt8[r];
    }
  }

  // ---- softmax + masked write + compact lists (per row) ----
#pragma unroll
  for (int r = 0; r < 4; ++r) {
    const float thresh = T[r];
    float e16[16];
    float zl = 0.0f;
#pragma unroll
    for (int j = 0; j < 16; ++j) {
      const bool kept = (acc[r][j] >= thresh);
      const float e = kept ? __expf((acc[r][j] - rowmax[r]) * 0.125f) : 0.0f;
      e16[j] = e;
      zl += e;
    }
    const float zsum = dpp_fsum64(zl);
    const float inv = 1.0f / zsum;

    const long long row = row0 + wv * 4 + r;
    float* a = A + (row << 10);
    int cnt = 0;
#pragma unroll
    for (int j = 0; j < 16; ++j) {
      const bool kept = (acc[r][j] >= thresh);
      const float w = e16[j] * inv;
      e16[j] = kept ? w : 0.0f;
      const unsigned long long mk = __ballot(kept);
      if (kept) {
        const int pos = cnt + __popcll(mk & ((1ull << u) - 1ull));
        if (pos < 16) {
          const int col = (j >> 2) * 256 + 4 * u + (j & 3);
          outIdx[row * 16 + pos] = col;
          outW[row * 16 + pos] = w;
        }
      }
      cnt += __popcll(mk);
    }
    if (u == 0) outCnt[row] = cnt < 16 ? cnt : 16;

#pragma unroll
    for (int blkc = 0; blkc < 4; ++blkc) {
      float4 o;
      o.x = e16[blkc * 4 + 0];
      o.y = e16[blkc * 4 + 1];
      o.z = e16[blkc * 4 + 2];
      o.w = e16[blkc * 4 + 3];
      *reinterpret_cast<float4*>(&a[blkc * 256 + 4 * u]) = o;
    }
  }
}

// ---------------------------------------------------------------------------
// Sparse A*v from compact lists. One wave per row (lane = e).
// ---------------------------------------------------------------------------
__global__ __launch_bounds__(256) void vagg_kernel(
    const int* __restrict__ idx, const float* __restrict__ w,
    const int* __restrict__ cnt, const float* __restrict__ Vp,
    float* __restrict__ Vagg) {
  const int wave = threadIdx.x >> 6;
  const int lane = threadIdx.x & 63;
  const long long row = (long long)blockIdx.x * 4 + wave;
  const int b = (int)(row >> 14);
  const int h = (int)((row >> 10) & 15);
  const int l = (int)(row & 1023);
  const int n = cnt[row];
  float acc = 0.0f;
  for (int i = 0; i < n; ++i) {
    const int sI = idx[row * 16 + i];
    const float ww = w[row * 16 + i];
    acc += ww * Vp[((long long)((b << 10) + sI) << 10) + (h << 6) + lane];
  }
  Vagg[((long long)((b << 10) + l) << 10) + (h << 6) + lane] = acc;
}

extern "C" void kernel_launch(void* const* d_in, const int* in_sizes, int n_in,
                              void* d_out, int out_size, void* d_ws,
                              size_t ws_size, hipStream_t stream) {
  const float* queries = (const float*)d_in[0];
  const float* keys = (const float*)d_in[1];
  const float* values = (const float*)d_in[2];
  const float* Wq = (const float*)d_in[3];
  const float* bq = (const float*)d_in[4];
  const float* Wk = (const float*)d_in[5];
  const float* bk = (const float*)d_in[6];
  const float* Wv = (const float*)d_in[7];
  const float* bv = (const float*)d_in[8];
  const float* Wo = (const float*)d_in[9];
  const float* bo = (const float*)d_in[10];

  float* out = (float*)d_out;                   // [B,L,D]
  float* Aout = out + (long long)B_ * L_ * D_;  // [B,H,L,S]

  char* ws = (char*)d_ws;
  const size_t MD = (size_t)B_ * L_ * D_ * sizeof(float);  // 33.55 MB
  const size_t NL = (size_t)B_ * H_ * L_;                   // 131072 rows
  float* Qf = (float*)ws;
  float* Kf = (float*)(ws + MD);
  float* Kt = (float*)(ws + 2 * MD);
  int* tIdx = (int*)(ws + 3 * MD);
  float* tW = (float*)(ws + 3 * MD + NL * 16 * 4);
  int* tCnt = (int*)(ws + 3 * MD + NL * 16 * 8);
  float* Vb = (float*)(ws + 3 * MD + NL * 16 * 8 + NL * 4);
  float* Vagg = Kt;  // Kt dead after score_topk_fused

  const dim3 blk(256);
  const int M = B_ * L_;  // 8192

  // Q = relu(queries @ Wq^T + bq)   [bit-exact chain]
  gemm_abt<1><<<dim3(16, M / 64), blk, 0, stream>>>(queries, Wq, bq, Qf, M, D_,
                                                    D_, D_, D_, D_);
  // K = keys @ Wk^T + bk            [bit-exact chain]
  gemm_abt<0><<<dim3(16, M / 64), blk, 0, stream>>>(keys, Wk, bk, Kf, M, D_,
                                                    D_, D_, D_, D_);
  // Kt[b,h,e,s] = Kf[b,s,h,e]
  transpose_k<<<dim3(16, B_ * H_), blk, 0, stream>>>(Kf, Kt);

  // fused scores + top-8 + softmax -> A + compact lists
  score_topk_fused<<<(int)(NL / 16), blk, 0, stream>>>(Qf, Kt, Aout, tIdx, tW,
                                                       tCnt);

  // V = relu(values @ Wv^T + bv)
  gemm_abt<1><<<dim3(16, M / 64), blk, 0, stream>>>(values, Wv, bv, Vb, M, D_,
                                                    D_, D_, D_, D_);

  // Vagg[b,l,h,:] = sum_s A * v   (writes into Kt slot)
  vagg_kernel<<<(int)(NL / 4), blk, 0, stream>>>(tIdx, tW, tCnt, Vb, Vagg);

  // out = Vagg @ Wo^T + bo
  gemm_abt<0><<<dim3(16, M / 64), blk, 0, stream>>>(Vagg, Wo, bo, out, M, D_,
                                                    D_, D_, D_, D_);
}